// Round 1
// baseline (1063.499 us; speedup 1.0000x reference)
//
#include <hip/hip_runtime.h>
#include <hip/hip_bf16.h>
#include <stdint.h>

// Problem constants: x (8,2048,4096) fp32 -> M=16384 rows, K=4096; W (4096x4096); out fp32.
#define M_DIM 16384
#define N_DIM 4096
#define K_DIM 4096

typedef short short8 __attribute__((ext_vector_type(8)));      // 8 bf16 (4 VGPRs) MFMA frag
typedef unsigned short ushort8 __attribute__((ext_vector_type(8)));
typedef float f32x4 __attribute__((ext_vector_type(4)));

// fp32 -> bf16 with round-to-nearest-even
__device__ __forceinline__ unsigned short f2b(float f) {
    union { float f; uint32_t u; } v; v.f = f;
    return (unsigned short)((v.u + 0x7FFFu + ((v.u >> 16) & 1u)) >> 16);
}

// async global->LDS, 16B per lane. LDS dest is wave-uniform base + lane*16.
__device__ __forceinline__ void async_ld16(const void* g, void* l) {
    __builtin_amdgcn_global_load_lds(
        (const __attribute__((address_space(1))) uint32_t*)g,
        (__attribute__((address_space(3))) uint32_t*)l, 16, 0, 0);
}

// ---------------------------------------------------------------------------
// Build W[o][c] = sum_b A[b, i, j] * B[b, k, m],  o = i*64+k, c = j*64+m.
// Row-major [N_DIM][K_DIM], bf16. One thread -> 8 consecutive c (same i,k,j).
// ---------------------------------------------------------------------------
__global__ __launch_bounds__(256) void build_w_kernel(
    const float* __restrict__ A, const float* __restrict__ B,
    unsigned short* __restrict__ W)
{
    size_t idx = ((size_t)blockIdx.x * 256 + threadIdx.x) * 8;
    int o = (int)(idx >> 12);        // / 4096
    int c = (int)(idx & 4095);
    int i = o >> 6, k = o & 63;
    int j = c >> 6, m0 = c & 63;     // m0 is 8-aligned

    float acc[8];
#pragma unroll
    for (int t = 0; t < 8; ++t) acc[t] = 0.0f;
#pragma unroll
    for (int b = 0; b < 8; ++b) {
        float a = A[b * 4096 + i * 64 + j];
        const float4* bp = (const float4*)&B[b * 4096 + k * 64 + m0];
        float4 b0 = bp[0], b1 = bp[1];
        acc[0] += a * b0.x; acc[1] += a * b0.y;
        acc[2] += a * b0.z; acc[3] += a * b0.w;
        acc[4] += a * b1.x; acc[5] += a * b1.y;
        acc[6] += a * b1.z; acc[7] += a * b1.w;
    }
    ushort8 r;
#pragma unroll
    for (int t = 0; t < 8; ++t) r[t] = f2b(acc[t]);
    *(ushort8*)&W[idx] = r;          // 16B store
}

// ---------------------------------------------------------------------------
// Convert x fp32 -> bf16 (for the pure global_load_lds GEMM path).
// ---------------------------------------------------------------------------
__global__ __launch_bounds__(256) void cvt_x_kernel(
    const float* __restrict__ x, unsigned short* __restrict__ xb)
{
    size_t idx = ((size_t)blockIdx.x * 256 + threadIdx.x) * 8;
    const float4* gp = (const float4*)&x[idx];
    float4 v0 = gp[0], v1 = gp[1];
    ushort8 r;
    r[0] = f2b(v0.x); r[1] = f2b(v0.y); r[2] = f2b(v0.z); r[3] = f2b(v0.w);
    r[4] = f2b(v1.x); r[5] = f2b(v1.y); r[6] = f2b(v1.z); r[7] = f2b(v1.w);
    *(ushort8*)&xb[idx] = r;
}

// ---------------------------------------------------------------------------
// m97-style GEMM: out[s,o] = sum_c x[s,c]*W[o,c] + bias[o]
// 128x128 tile, BK=32, 256 threads (4 waves, 2x2 of 64x64), 16x16x32 bf16 MFMA.
// A-operand: x (M=s, K=c) staged as As[m][k]; B-operand: W[o][c] staged Bs[n][k].
// PRECONV: A staged via global_load_lds from pre-converted bf16 x.
// ---------------------------------------------------------------------------
template <bool PRECONV>
__global__ __launch_bounds__(256, 2) void gemm_kernel(
    const float* __restrict__ xf,
    const unsigned short* __restrict__ xb,
    const unsigned short* __restrict__ W,
    const float* __restrict__ bias,
    float* __restrict__ out)
{
    __shared__ unsigned short As[128 * 32];
    __shared__ unsigned short Bs[128 * 32];

    const int tid = threadIdx.x;
    const int wave = tid >> 6;
    const int lane = tid & 63;
    const int quad = lane >> 4;
    const int l15 = lane & 15;
    const int wm = (wave >> 1) * 64;   // wave's M offset in tile
    const int wn = (wave & 1) * 64;    // wave's N offset in tile
    const size_t mbase = (size_t)blockIdx.y * 128;
    const int nbase = blockIdx.x * 128;

    f32x4 acc[4][4];
#pragma unroll
    for (int a = 0; a < 4; ++a)
#pragma unroll
        for (int b = 0; b < 4; ++b)
            acc[a][b] = (f32x4){0.0f, 0.0f, 0.0f, 0.0f};

    for (int k0 = 0; k0 < K_DIM; k0 += 32) {
        // ---- stage B tile (W rows nbase..nbase+127, 32 k) : async 16B ----
        {
            const int issue0 = wave * 2;
#pragma unroll
            for (int t = 0; t < 2; ++t) {
                const int isn = issue0 + t;                 // 0..7, covers 16 rows each
                const int row = isn * 16 + (lane >> 2);
                const int kc = (lane & 3) * 8;
                async_ld16(&W[(size_t)(nbase + row) * K_DIM + k0 + kc],
                           &Bs[isn * 512]);
            }
        }
        // ---- stage A tile (x rows mbase..mbase+127, 32 k) ----
        if (PRECONV) {
            const int issue0 = wave * 2;
#pragma unroll
            for (int t = 0; t < 2; ++t) {
                const int isn = issue0 + t;
                const int row = isn * 16 + (lane >> 2);
                const int kc = (lane & 3) * 8;
                async_ld16(&xb[(mbase + row) * K_DIM + k0 + kc],
                           &As[isn * 512]);
            }
        } else {
            // fp32 load + convert: thread -> 16 floats of one row-half
            const int row = tid >> 1;
            const int half = tid & 1;
            const float* gp = xf + (mbase + row) * K_DIM + k0 + half * 16;
            float4 v0 = ((const float4*)gp)[0];
            float4 v1 = ((const float4*)gp)[1];
            float4 v2 = ((const float4*)gp)[2];
            float4 v3 = ((const float4*)gp)[3];
            ushort8 lo, hi;
            lo[0] = f2b(v0.x); lo[1] = f2b(v0.y); lo[2] = f2b(v0.z); lo[3] = f2b(v0.w);
            lo[4] = f2b(v1.x); lo[5] = f2b(v1.y); lo[6] = f2b(v1.z); lo[7] = f2b(v1.w);
            hi[0] = f2b(v2.x); hi[1] = f2b(v2.y); hi[2] = f2b(v2.z); hi[3] = f2b(v2.w);
            hi[4] = f2b(v3.x); hi[5] = f2b(v3.y); hi[6] = f2b(v3.z); hi[7] = f2b(v3.w);
            *(ushort8*)&As[row * 32 + half * 16] = lo;
            *(ushort8*)&As[row * 32 + half * 16 + 8] = hi;
        }
        __syncthreads();

        // ---- LDS -> frags -> MFMA ----
        short8 af[4], bf[4];
#pragma unroll
        for (int mt = 0; mt < 4; ++mt)
            af[mt] = *(const short8*)&As[(wm + mt * 16 + l15) * 32 + quad * 8];
#pragma unroll
        for (int nt = 0; nt < 4; ++nt)
            bf[nt] = *(const short8*)&Bs[(wn + nt * 16 + l15) * 32 + quad * 8];
#pragma unroll
        for (int mt = 0; mt < 4; ++mt)
#pragma unroll
            for (int nt = 0; nt < 4; ++nt)
                acc[mt][nt] = __builtin_amdgcn_mfma_f32_16x16x32_bf16(
                    af[mt], bf[nt], acc[mt][nt], 0, 0, 0);
        __syncthreads();
    }

    // ---- epilogue: C/D layout row=quad*4+r, col=lane&15; add bias, store fp32
    float bv[4];
#pragma unroll
    for (int nt = 0; nt < 4; ++nt) bv[nt] = bias[nbase + wn + nt * 16 + l15];
#pragma unroll
    for (int mt = 0; mt < 4; ++mt) {
#pragma unroll
        for (int r = 0; r < 4; ++r) {
            const size_t row = mbase + wm + mt * 16 + quad * 4 + r;
            float* orow = out + row * N_DIM + nbase + wn + l15;
#pragma unroll
            for (int nt = 0; nt < 4; ++nt)
                orow[nt * 16] = acc[mt][nt][r] + bv[nt];
        }
    }
}

// ---------------------------------------------------------------------------
extern "C" void kernel_launch(void* const* d_in, const int* in_sizes, int n_in,
                              void* d_out, int out_size, void* d_ws, size_t ws_size,
                              hipStream_t stream)
{
    const float* x = (const float*)d_in[0];     // (8,2048,4096)
    const float* A = (const float*)d_in[1];     // (8,64,64)
    const float* B = (const float*)d_in[2];     // (8,64,64)
    const float* bias = (const float*)d_in[3];  // (4096,)
    float* out = (float*)d_out;

    unsigned short* Wb = (unsigned short*)d_ws;             // 32 MB bf16 W
    const size_t wbytes = (size_t)N_DIM * K_DIM * 2;
    const size_t xbytes = (size_t)M_DIM * K_DIM * 2;

    // W must be rebuilt every call (ws is re-poisoned before every timed launch)
    build_w_kernel<<<(N_DIM * (size_t)K_DIM) / 8 / 256, 256, 0, stream>>>(A, B, Wb);

    if (ws_size >= wbytes + xbytes) {
        unsigned short* xbuf = (unsigned short*)((char*)d_ws + wbytes);
        cvt_x_kernel<<<((size_t)M_DIM * K_DIM) / 8 / 256, 256, 0, stream>>>(x, xbuf);
        gemm_kernel<true><<<dim3(N_DIM / 128, M_DIM / 128), 256, 0, stream>>>(
            nullptr, xbuf, Wb, bias, out);
    } else {
        gemm_kernel<false><<<dim3(N_DIM / 128, M_DIM / 128), 256, 0, stream>>>(
            x, nullptr, Wb, bias, out);
    }
}